// Round 1
// baseline (199.410 us; speedup 1.0000x reference)
//
#include <hip/hip_runtime.h>

#define B_    2
#define N1_   256
#define N2_   256
#define DIN_  1024
#define DRED_ 512
#define DREP_ 1024

#define TM 64
#define TN 64
#define TK 16

// Dual-tenant tiled fp32 GEMM: blockIdx.z selects (A,W,bias,C) tenant.
// C = act(A @ W + bias), A: MxK row-major, W: KxN row-major.
__global__ __launch_bounds__(256) void gemm_dual(
    const float* __restrict__ Aa, const float* __restrict__ Ab,
    const float* __restrict__ Wa, const float* __restrict__ Wb,
    const float* __restrict__ biasa, const float* __restrict__ biasb,
    float* __restrict__ Ca, float* __restrict__ Cb,
    int M, int K, int N, int doRelu)
{
    const float* A    = (blockIdx.z == 0) ? Aa : Ab;
    const float* W    = (blockIdx.z == 0) ? Wa : Wb;
    const float* bias = (blockIdx.z == 0) ? biasa : biasb;
    float*       C    = (blockIdx.z == 0) ? Ca : Cb;

    __shared__ float As[TK][TM];   // transposed A tile: As[k][m]
    __shared__ float Ws[TK][TN];   // Ws[k][n]

    const int tid = threadIdx.x;   // 0..255
    const int tx  = tid & 15;      // n-direction (16)
    const int ty  = tid >> 4;      // m-direction (16)
    const int m0  = blockIdx.y * TM;
    const int n0  = blockIdx.x * TN;

    // global->LDS load indices
    const int arow = tid >> 2;          // 0..63  (m within tile)
    const int acol = (tid & 3) << 2;    // 0,4,8,12 (k within tile)
    const int wrow = tid >> 4;          // 0..15  (k within tile)
    const int wcol = (tid & 15) << 2;   // 0..60  (n within tile)

    float acc[4][4] = {{0.f}};

    for (int k0 = 0; k0 < K; k0 += TK) {
        float4 av = *reinterpret_cast<const float4*>(
            &A[(size_t)(m0 + arow) * K + k0 + acol]);
        As[acol + 0][arow] = av.x;
        As[acol + 1][arow] = av.y;
        As[acol + 2][arow] = av.z;
        As[acol + 3][arow] = av.w;
        float4 wv = *reinterpret_cast<const float4*>(
            &W[(size_t)(k0 + wrow) * N + n0 + wcol]);
        *reinterpret_cast<float4*>(&Ws[wrow][wcol]) = wv;
        __syncthreads();

        #pragma unroll
        for (int kk = 0; kk < TK; ++kk) {
            float4 a = *reinterpret_cast<const float4*>(&As[kk][ty << 2]);
            float4 w = *reinterpret_cast<const float4*>(&Ws[kk][tx << 2]);
            float af[4] = {a.x, a.y, a.z, a.w};
            float wf[4] = {w.x, w.y, w.z, w.w};
            #pragma unroll
            for (int i = 0; i < 4; ++i)
                #pragma unroll
                for (int j = 0; j < 4; ++j)
                    acc[i][j] = fmaf(af[i], wf[j], acc[i][j]);
        }
        __syncthreads();
    }

    // epilogue: bias + optional relu, float4 stores
    #pragma unroll
    for (int i = 0; i < 4; ++i) {
        const int m = m0 + (ty << 2) + i;
        const int n = n0 + (tx << 2);
        float4 v;
        v.x = acc[i][0]; v.y = acc[i][1]; v.z = acc[i][2]; v.w = acc[i][3];
        if (bias) {
            const float4 bv = *reinterpret_cast<const float4*>(&bias[n]);
            v.x += bv.x; v.y += bv.y; v.z += bv.z; v.w += bv.w;
        }
        if (doRelu) {
            v.x = fmaxf(v.x, 0.f); v.y = fmaxf(v.y, 0.f);
            v.z = fmaxf(v.z, 0.f); v.w = fmaxf(v.w, 0.f);
        }
        *reinterpret_cast<float4*>(&C[(size_t)m * N + n]) = v;
    }
}

// out[b,n,m,:] = relu(A1[b,n,:] + A2[b,m,:]); one block = one (b,n) x 4 m-rows.
__global__ __launch_bounds__(256) void bcast_relu(
    const float4* __restrict__ A1,   // (B*N1) x DREP/4
    const float4* __restrict__ A2,   // (B*N2) x DREP/4
    float4* __restrict__ out)        // (B*N1*N2) x DREP/4
{
    const int RW = DREP_ / 4;        // 256 float4 per row
    const int MG = N2_ / 4;          // m-groups per (b,n)
    const int t  = threadIdx.x;      // 0..255

    const int blk = blockIdx.x;
    const int mg  = blk % MG;
    const int bn  = blk / MG;        // b*N1 + n
    const int b   = bn / N1_;

    const float4 a1 = A1[(size_t)bn * RW + t];
    const float4* a2b = A2 + ((size_t)b * N2_ + (size_t)mg * 4) * RW + t;
    float4* ob = out + ((size_t)bn * N2_ + (size_t)mg * 4) * RW + t;

    #pragma unroll
    for (int i = 0; i < 4; ++i) {
        const float4 a2 = a2b[(size_t)i * RW];
        float4 v;
        v.x = fmaxf(a1.x + a2.x, 0.f);
        v.y = fmaxf(a1.y + a2.y, 0.f);
        v.z = fmaxf(a1.z + a2.z, 0.f);
        v.w = fmaxf(a1.w + a2.w, 0.f);
        ob[(size_t)i * RW] = v;
    }
}

extern "C" void kernel_launch(void* const* d_in, const int* in_sizes, int n_in,
                              void* d_out, int out_size, void* d_ws, size_t ws_size,
                              hipStream_t stream) {
    const float* span1  = (const float*)d_in[0];
    const float* span2  = (const float*)d_in[1];
    const float* W_red  = (const float*)d_in[2];
    const float* b_red  = (const float*)d_in[3];
    const float* W_repr = (const float*)d_in[4];
    const float* b_repr = (const float*)d_in[5];
    float* out = (float*)d_out;

    float* ws = (float*)d_ws;
    float* r1 = ws;                          // 512*512
    float* r2 = r1 + 512 * 512;              // 512*512
    float* A1 = r2 + 512 * 512;              // 512*1024
    float* A2 = A1 + 512 * 1024;             // 512*1024

    const int M = B_ * N1_;                  // 512 (N1==N2 so same for spans)

    // Stage 1: r{1,2} = relu(span{1,2} @ W_red + b_red)
    dim3 g1(DRED_ / TN, M / TM, 2);          // (8, 8, 2)
    gemm_dual<<<g1, 256, 0, stream>>>(
        span1, span2, W_red, W_red, b_red, b_red, r1, r2,
        M, DIN_, DRED_, 1);

    // Stage 2: A1 = r1 @ Wa + b_repr ; A2 = r2 @ Wb
    const float* Wa = W_repr;                // rows 0..DRED-1
    const float* Wb = W_repr + (size_t)DRED_ * DREP_;
    dim3 g2(DREP_ / TN, M / TM, 2);          // (16, 8, 2)
    gemm_dual<<<g2, 256, 0, stream>>>(
        r1, r2, Wa, Wb, b_repr, nullptr, A1, A2,
        M, DRED_, DREP_, 0);

    // Stage 3: out = relu(A1[b,n,:] + A2[b,m,:])
    dim3 g3(B_ * N1_ * N2_ / 4);             // 32768 blocks
    bcast_relu<<<g3, 256, 0, stream>>>(
        (const float4*)A1, (const float4*)A2, (float4*)out);
}

// Round 3
// 145.345 us; speedup vs baseline: 1.3720x; 1.3720x over previous
//
#include <hip/hip_runtime.h>

#define B_    2
#define N1_   256
#define N2_   256
#define DIN_  1024
#define DRED_ 512
#define DREP_ 1024

typedef unsigned short ushort_t;
typedef float f32x4 __attribute__((ext_vector_type(4)));
typedef short bf16x8 __attribute__((ext_vector_type(8)));

__device__ __forceinline__ ushort_t f2bf(float x) {
    unsigned u = __builtin_bit_cast(unsigned, x);
    unsigned r = (u + 0x7fffu + ((u >> 16) & 1u)) >> 16;   // round-to-nearest-even
    return (ushort_t)r;
}
__device__ __forceinline__ float bf2f(ushort_t h) {
    unsigned u = ((unsigned)h) << 16;
    return __builtin_bit_cast(float, u);
}

__device__ __forceinline__ void mfma16(f32x4& acc, bf16x8 a, bf16x8 b) {
    acc = __builtin_amdgcn_mfma_f32_16x16x32_bf16(a, b, acc, 0, 0, 0);
}

// W [K][N] f32  ->  Th/Tl [N][K] bf16 bits (hi/lo split)
__global__ __launch_bounds__(256) void transpose_split(
    const float* __restrict__ W, ushort_t* __restrict__ Th,
    ushort_t* __restrict__ Tl, int K, int N)
{
    __shared__ float T[64][65];
    const int tid = threadIdx.x;
    const int n0 = blockIdx.x * 64;
    const int k0 = blockIdx.y * 64;
    #pragma unroll
    for (int p = 0; p < 4; ++p) {
        int r = (tid >> 4) + p * 16;
        int c = (tid & 15) * 4;
        float4 v = *reinterpret_cast<const float4*>(&W[(size_t)(k0 + r) * N + n0 + c]);
        T[r][c] = v.x; T[r][c + 1] = v.y; T[r][c + 2] = v.z; T[r][c + 3] = v.w;
    }
    __syncthreads();
    #pragma unroll
    for (int p = 0; p < 4; ++p) {
        int rn = (tid >> 4) + p * 16;
        int ck = (tid & 15) * 4;
        ushort_t hh[4], ll[4];
        #pragma unroll
        for (int j = 0; j < 4; ++j) {
            float v = T[ck + j][rn];
            hh[j] = f2bf(v);
            ll[j] = f2bf(v - bf2f(hh[j]));
        }
        *reinterpret_cast<ushort4*>(&Th[(size_t)(n0 + rn) * K + k0 + ck]) =
            ushort4{hh[0], hh[1], hh[2], hh[3]};
        *reinterpret_cast<ushort4*>(&Tl[(size_t)(n0 + rn) * K + k0 + ck]) =
            ushort4{ll[0], ll[1], ll[2], ll[3]};
    }
}

// Split-bf16 MFMA GEMM, dual tenant (blockIdx.z).
// MODE 0: A fp32 (split in staging), C = relu(A@B + bias) stored as hi/lo bf16.
// MODE 1: A = hi/lo bf16 pair, C = A@B (+ bias if non-null) stored fp32.
// B is pre-transposed [N][ldb] bf16 hi/lo; bOff selects k-slice of B rows.
template<int MODE>
__global__ __launch_bounds__(256) void gemm_split(
    const float* __restrict__ Af0, const float* __restrict__ Af1,
    const ushort_t* __restrict__ Ah0, const ushort_t* __restrict__ Al0,
    const ushort_t* __restrict__ Ah1, const ushort_t* __restrict__ Al1,
    const ushort_t* __restrict__ Bh, const ushort_t* __restrict__ Bl,
    int bOff0, int bOff1,
    const float* __restrict__ bias0, const float* __restrict__ bias1,
    ushort_t* __restrict__ Ch0, ushort_t* __restrict__ Cl0,
    ushort_t* __restrict__ Ch1, ushort_t* __restrict__ Cl1,
    float* __restrict__ Cf0, float* __restrict__ Cf1,
    int M, int N, int K, int lda, int ldb)
{
    __shared__ ushort_t Ash[64][72];
    __shared__ ushort_t Asl[64][72];
    __shared__ ushort_t Bsh[64][72];
    __shared__ ushort_t Bsl[64][72];

    const int tid = threadIdx.x;
    const int z = blockIdx.z;
    const int m0 = blockIdx.y * 64;
    const int n0 = blockIdx.x * 64;

    const float*    Af  = z ? Af1 : Af0;
    const ushort_t* Ah  = z ? Ah1 : Ah0;
    const ushort_t* Al  = z ? Al1 : Al0;
    const int       bOff = z ? bOff1 : bOff0;
    const float*    bias = z ? bias1 : bias0;

    const int lane = tid & 63;
    const int wid  = tid >> 6;
    const int m_w  = (wid >> 1) * 32;
    const int n_w  = (wid & 1) * 32;
    const int lrow = lane & 15;        // fragment row/col within 16
    const int lkg  = (lane >> 4) * 8;  // k-group offset (8 contiguous)

    f32x4 acc[2][2] = {};

    for (int k0 = 0; k0 < K; k0 += 64) {
        // ---- stage A tile (64 rows x 64 k) ----
        if (MODE == 0) {
            #pragma unroll
            for (int p = 0; p < 4; ++p) {
                int r = (tid >> 4) + p * 16;
                int c = (tid & 15) * 4;
                float4 v = *reinterpret_cast<const float4*>(&Af[(size_t)(m0 + r) * lda + k0 + c]);
                float vv[4] = {v.x, v.y, v.z, v.w};
                ushort_t hh[4], ll[4];
                #pragma unroll
                for (int j = 0; j < 4; ++j) {
                    hh[j] = f2bf(vv[j]);
                    ll[j] = f2bf(vv[j] - bf2f(hh[j]));
                }
                *reinterpret_cast<ushort4*>(&Ash[r][c]) = ushort4{hh[0], hh[1], hh[2], hh[3]};
                *reinterpret_cast<ushort4*>(&Asl[r][c]) = ushort4{ll[0], ll[1], ll[2], ll[3]};
            }
        } else {
            #pragma unroll
            for (int p = 0; p < 2; ++p) {
                int r = (tid >> 3) + p * 32;
                int c = (tid & 7) * 8;
                *reinterpret_cast<uint4*>(&Ash[r][c]) =
                    *reinterpret_cast<const uint4*>(&Ah[(size_t)(m0 + r) * lda + k0 + c]);
                *reinterpret_cast<uint4*>(&Asl[r][c]) =
                    *reinterpret_cast<const uint4*>(&Al[(size_t)(m0 + r) * lda + k0 + c]);
            }
        }
        // ---- stage B tile (64 n-rows x 64 k), already transposed/split ----
        #pragma unroll
        for (int p = 0; p < 2; ++p) {
            int r = (tid >> 3) + p * 32;
            int c = (tid & 7) * 8;
            *reinterpret_cast<uint4*>(&Bsh[r][c]) =
                *reinterpret_cast<const uint4*>(&Bh[(size_t)(n0 + r) * ldb + bOff + k0 + c]);
            *reinterpret_cast<uint4*>(&Bsl[r][c]) =
                *reinterpret_cast<const uint4*>(&Bl[(size_t)(n0 + r) * ldb + bOff + k0 + c]);
        }
        __syncthreads();

        #pragma unroll
        for (int s = 0; s < 2; ++s) {
            const int kk = s * 32 + lkg;
            bf16x8 ah[2], al[2], bh[2], bl[2];
            #pragma unroll
            for (int i = 0; i < 2; ++i) {
                ah[i] = *reinterpret_cast<const bf16x8*>(&Ash[m_w + i * 16 + lrow][kk]);
                al[i] = *reinterpret_cast<const bf16x8*>(&Asl[m_w + i * 16 + lrow][kk]);
                bh[i] = *reinterpret_cast<const bf16x8*>(&Bsh[n_w + i * 16 + lrow][kk]);
                bl[i] = *reinterpret_cast<const bf16x8*>(&Bsl[n_w + i * 16 + lrow][kk]);
            }
            #pragma unroll
            for (int mi = 0; mi < 2; ++mi)
                #pragma unroll
                for (int ni = 0; ni < 2; ++ni) {
                    mfma16(acc[mi][ni], ah[mi], bh[ni]);
                    mfma16(acc[mi][ni], ah[mi], bl[ni]);
                    mfma16(acc[mi][ni], al[mi], bh[ni]);
                }
        }
        __syncthreads();
    }

    ushort_t* Ch = z ? Ch1 : Ch0;
    ushort_t* Cl = z ? Cl1 : Cl0;
    float*    Cf = z ? Cf1 : Cf0;

    #pragma unroll
    for (int mi = 0; mi < 2; ++mi)
        #pragma unroll
        for (int ni = 0; ni < 2; ++ni)
            #pragma unroll
            for (int j = 0; j < 4; ++j) {
                int m = m0 + m_w + mi * 16 + (lane >> 4) * 4 + j;
                int n = n0 + n_w + ni * 16 + (lane & 15);
                float v = acc[mi][ni][j];
                if (MODE == 0) {
                    v += bias[n];
                    v = fmaxf(v, 0.f);
                    ushort_t h = f2bf(v);
                    Ch[(size_t)m * N + n] = h;
                    Cl[(size_t)m * N + n] = f2bf(v - bf2f(h));
                } else {
                    if (bias) v += bias[n];
                    Cf[(size_t)m * N + n] = v;
                }
            }
}

// out[b,n,m,:] = relu(A1[b,n,:] + A2[b,m,:]); one block = one (b,n) x 4 m-rows.
__global__ __launch_bounds__(256) void bcast_relu(
    const float4* __restrict__ A1, const float4* __restrict__ A2,
    float4* __restrict__ out)
{
    const int RW = DREP_ / 4;
    const int MG = N2_ / 4;
    const int t  = threadIdx.x;

    const int blk = blockIdx.x;
    const int mg  = blk % MG;
    const int bn  = blk / MG;
    const int b   = bn / N1_;

    const float4 a1 = A1[(size_t)bn * RW + t];
    const float4* a2b = A2 + ((size_t)b * N2_ + (size_t)mg * 4) * RW + t;
    float4* ob = out + ((size_t)bn * N2_ + (size_t)mg * 4) * RW + t;

    #pragma unroll
    for (int i = 0; i < 4; ++i) {
        const float4 a2 = a2b[(size_t)i * RW];
        float4 v;
        v.x = fmaxf(a1.x + a2.x, 0.f);
        v.y = fmaxf(a1.y + a2.y, 0.f);
        v.z = fmaxf(a1.z + a2.z, 0.f);
        v.w = fmaxf(a1.w + a2.w, 0.f);
        ob[(size_t)i * RW] = v;
    }
}

extern "C" void kernel_launch(void* const* d_in, const int* in_sizes, int n_in,
                              void* d_out, int out_size, void* d_ws, size_t ws_size,
                              hipStream_t stream) {
    const float* span1  = (const float*)d_in[0];
    const float* span2  = (const float*)d_in[1];
    const float* W_red  = (const float*)d_in[2];
    const float* b_red  = (const float*)d_in[3];
    const float* W_repr = (const float*)d_in[4];
    const float* b_repr = (const float*)d_in[5];
    float* out = (float*)d_out;

    // workspace carve (12 MB total)
    float* A1 = (float*)d_ws;                       // 512*1024 f32
    float* A2 = A1 + 512 * 1024;                    // 512*1024 f32
    ushort_t* p = (ushort_t*)(A2 + 512 * 1024);
    ushort_t* r1h = p;  p += 512 * 512;
    ushort_t* r1l = p;  p += 512 * 512;
    ushort_t* r2h = p;  p += 512 * 512;
    ushort_t* r2l = p;  p += 512 * 512;
    ushort_t* Wrth = p; p += 512 * 1024;            // W_red^T  [512][1024]
    ushort_t* Wrtl = p; p += 512 * 1024;
    ushort_t* Wpth = p; p += 1024 * 1024;           // W_repr^T [1024][1024]
    ushort_t* Wptl = p; p += 1024 * 1024;

    // weight transpose + hi/lo split
    transpose_split<<<dim3(DRED_ / 64, DIN_ / 64), 256, 0, stream>>>(
        W_red, Wrth, Wrtl, DIN_, DRED_);
    transpose_split<<<dim3(DREP_ / 64, (2 * DRED_) / 64), 256, 0, stream>>>(
        W_repr, Wpth, Wptl, 2 * DRED_, DREP_);

    const int M = B_ * N1_;   // 512

    // stage 1: r{1,2} = relu(span{1,2} @ W_red + b_red), stored hi/lo bf16
    gemm_split<0><<<dim3(DRED_ / 64, M / 64, 2), 256, 0, stream>>>(
        span1, span2, nullptr, nullptr, nullptr, nullptr,
        Wrth, Wrtl, 0, 0, b_red, b_red,
        r1h, r1l, r2h, r2l, nullptr, nullptr,
        M, DRED_, DIN_, DIN_, DIN_);

    // stage 2: A1 = r1 @ Wa + b_repr ; A2 = r2 @ Wb
    gemm_split<1><<<dim3(DREP_ / 64, M / 64, 2), 256, 0, stream>>>(
        nullptr, nullptr, r1h, r1l, r2h, r2l,
        Wpth, Wptl, 0, DRED_, b_repr, nullptr,
        nullptr, nullptr, nullptr, nullptr, A1, A2,
        M, DREP_, DRED_, DRED_, 2 * DRED_);

    // stage 3: broadcast + relu
    bcast_relu<<<dim3(B_ * N1_ * N2_ / 4), 256, 0, stream>>>(
        (const float4*)A1, (const float4*)A2, (float4*)out);
}

// Round 4
// 143.825 us; speedup vs baseline: 1.3865x; 1.0106x over previous
//
#include <hip/hip_runtime.h>

#define B_    2
#define N1_   256
#define N2_   256
#define DIN_  1024
#define DRED_ 512
#define DREP_ 1024

typedef unsigned short ushort_t;
typedef float f32x4 __attribute__((ext_vector_type(4)));
typedef short bf16x8 __attribute__((ext_vector_type(8)));

__device__ __forceinline__ ushort_t f2bf(float x) {
    unsigned u = __builtin_bit_cast(unsigned, x);
    unsigned r = (u + 0x7fffu + ((u >> 16) & 1u)) >> 16;   // RNE
    return (ushort_t)r;
}
__device__ __forceinline__ float bf2f(ushort_t h) {
    unsigned u = ((unsigned)h) << 16;
    return __builtin_bit_cast(float, u);
}
__device__ __forceinline__ void mfma16(f32x4& acc, bf16x8 a, bf16x8 b) {
    acc = __builtin_amdgcn_mfma_f32_16x16x32_bf16(a, b, acc, 0, 0, 0);
}

// Split-bf16 MFMA GEMM with fused on-the-fly weight transpose+split.
// Tile: BM=32, BN=64, BK=64. 4 waves, each 16m x 32n (2 frags).
// MODE 0: A fp32 (split during staging); C = relu(A@W + bias) -> hi/lo bf16.
// MODE 1: A hi/lo bf16; C = A@W (+bias if non-null) -> fp32.
// W is NATIVE [K][N] fp32 (row-major, n contiguous); bOff selects k-row base.
template<int MODE>
__global__ __launch_bounds__(256) void gemm_fused(
    const float* __restrict__ Af0, const float* __restrict__ Af1,
    const ushort_t* __restrict__ Ah0, const ushort_t* __restrict__ Al0,
    const ushort_t* __restrict__ Ah1, const ushort_t* __restrict__ Al1,
    const float* __restrict__ Wsrc,
    int bOff0, int bOff1,
    const float* __restrict__ bias0, const float* __restrict__ bias1,
    ushort_t* __restrict__ Ch0, ushort_t* __restrict__ Cl0,
    ushort_t* __restrict__ Ch1, ushort_t* __restrict__ Cl1,
    float* __restrict__ Cf0, float* __restrict__ Cf1,
    int M, int N, int K, int lda, int ldbn)
{
    __shared__ ushort_t Ash[32][72];
    __shared__ ushort_t Asl[32][72];
    __shared__ ushort_t Bsh[64][72];   // transposed: [n][k]
    __shared__ ushort_t Bsl[64][72];

    const int tid = threadIdx.x;
    const int z  = blockIdx.z;
    const int m0 = blockIdx.y * 32;
    const int n0 = blockIdx.x * 64;

    const float*    Af   = z ? Af1 : Af0;
    const ushort_t* Ah   = z ? Ah1 : Ah0;
    const ushort_t* Al   = z ? Al1 : Al0;
    const int       bOff = z ? bOff1 : bOff0;
    const float*    bias = z ? bias1 : bias0;

    const int lane = tid & 63;
    const int w    = tid >> 6;
    const int m_w  = (w >> 1) * 16;     // 0 or 16
    const int n_w  = (w & 1) * 32;      // 0 or 32
    const int lrow = lane & 15;
    const int lkg  = (lane >> 4) * 8;

    // staging indices
    const int ar = tid >> 3;            // 0..31 (m)
    const int ac4 = (tid & 7) * 4;      // MODE0: 4-f32 column group
    const int ac8 = (tid & 7) * 8;      // MODE1: 8-ushort column group
    const int bkp = tid >> 4;           // 0..15 (k-pair index)
    const int bn4 = (tid & 15) * 4;     // n group of 4

    f32x4 acc[2] = {};

    for (int k0 = 0; k0 < K; k0 += 64) {
        // ---- stage A (32 x 64) ----
        if (MODE == 0) {
            #pragma unroll
            for (int p = 0; p < 2; ++p) {
                const int c = ac4 + 32 * p;
                float4 v = *reinterpret_cast<const float4*>(
                    &Af[(size_t)(m0 + ar) * lda + k0 + c]);
                float vv[4] = {v.x, v.y, v.z, v.w};
                ushort_t hh[4], ll[4];
                #pragma unroll
                for (int j = 0; j < 4; ++j) {
                    hh[j] = f2bf(vv[j]);
                    ll[j] = f2bf(vv[j] - bf2f(hh[j]));
                }
                *reinterpret_cast<ushort4*>(&Ash[ar][c]) = ushort4{hh[0], hh[1], hh[2], hh[3]};
                *reinterpret_cast<ushort4*>(&Asl[ar][c]) = ushort4{ll[0], ll[1], ll[2], ll[3]};
            }
        } else {
            *reinterpret_cast<uint4*>(&Ash[ar][ac8]) =
                *reinterpret_cast<const uint4*>(&Ah[(size_t)(m0 + ar) * lda + k0 + ac8]);
            *reinterpret_cast<uint4*>(&Asl[ar][ac8]) =
                *reinterpret_cast<const uint4*>(&Al[(size_t)(m0 + ar) * lda + k0 + ac8]);
        }
        // ---- stage W (64k x 64n) transposed+split into Bsh/Bsl[n][k] ----
        #pragma unroll
        for (int p = 0; p < 2; ++p) {
            const int k = 2 * bkp + 32 * p;
            const float* src = Wsrc + (size_t)(bOff + k0 + k) * ldbn + n0 + bn4;
            float4 v0 = *reinterpret_cast<const float4*>(src);
            float4 v1 = *reinterpret_cast<const float4*>(src + ldbn);
            float a0[4] = {v0.x, v0.y, v0.z, v0.w};
            float a1[4] = {v1.x, v1.y, v1.z, v1.w};
            #pragma unroll
            for (int j = 0; j < 4; ++j) {
                ushort_t h0 = f2bf(a0[j]);
                ushort_t l0 = f2bf(a0[j] - bf2f(h0));
                ushort_t h1 = f2bf(a1[j]);
                ushort_t l1 = f2bf(a1[j] - bf2f(h1));
                *reinterpret_cast<ushort2*>(&Bsh[bn4 + j][k]) = ushort2{h0, h1};
                *reinterpret_cast<ushort2*>(&Bsl[bn4 + j][k]) = ushort2{l0, l1};
            }
        }
        __syncthreads();

        #pragma unroll
        for (int s = 0; s < 2; ++s) {
            const int kk = s * 32 + lkg;
            bf16x8 ah = *reinterpret_cast<const bf16x8*>(&Ash[m_w + lrow][kk]);
            bf16x8 al = *reinterpret_cast<const bf16x8*>(&Asl[m_w + lrow][kk]);
            #pragma unroll
            for (int ni = 0; ni < 2; ++ni) {
                bf16x8 bh = *reinterpret_cast<const bf16x8*>(&Bsh[n_w + ni * 16 + lrow][kk]);
                bf16x8 bl = *reinterpret_cast<const bf16x8*>(&Bsl[n_w + ni * 16 + lrow][kk]);
                mfma16(acc[ni], ah, bh);
                mfma16(acc[ni], ah, bl);
                mfma16(acc[ni], al, bh);
            }
        }
        __syncthreads();
    }

    ushort_t* Ch = z ? Ch1 : Ch0;
    ushort_t* Cl = z ? Cl1 : Cl0;
    float*    Cf = z ? Cf1 : Cf0;

    #pragma unroll
    for (int ni = 0; ni < 2; ++ni)
        #pragma unroll
        for (int j = 0; j < 4; ++j) {
            const int m = m0 + m_w + (lane >> 4) * 4 + j;
            const int n = n0 + n_w + ni * 16 + (lane & 15);
            float v = acc[ni][j];
            if (MODE == 0) {
                v += bias[n];
                v = fmaxf(v, 0.f);
                ushort_t h = f2bf(v);
                Ch[(size_t)m * N + n] = h;
                Cl[(size_t)m * N + n] = f2bf(v - bf2f(h));
            } else {
                if (bias) v += bias[n];
                Cf[(size_t)m * N + n] = v;
            }
        }
}

// out[b,n,m,:] = relu(A1[b,n,:] + A2[b,m,:]); one block = one (b,n) x 8 m-rows.
__global__ __launch_bounds__(256) void bcast_relu(
    const f32x4* __restrict__ A1, const f32x4* __restrict__ A2,
    f32x4* __restrict__ out)
{
    const int RW = DREP_ / 4;        // 256 f32x4 per row
    const int MG = N2_ / 8;          // 32 m-groups per (b,n)
    const int t  = threadIdx.x;

    const int blk = blockIdx.x;
    const int mg  = blk % MG;
    const int bn  = blk / MG;        // b*N1 + n
    const int b   = bn / N1_;

    const f32x4 a1 = A1[(size_t)bn * RW + t];
    const f32x4* a2b = A2 + ((size_t)b * N2_ + (size_t)mg * 8) * RW + t;
    f32x4* ob = out + ((size_t)bn * N2_ + (size_t)mg * 8) * RW + t;

    #pragma unroll
    for (int i = 0; i < 8; ++i) {
        const f32x4 a2 = a2b[(size_t)i * RW];
        f32x4 v;
        v.x = fmaxf(a1.x + a2.x, 0.f);
        v.y = fmaxf(a1.y + a2.y, 0.f);
        v.z = fmaxf(a1.z + a2.z, 0.f);
        v.w = fmaxf(a1.w + a2.w, 0.f);
        __builtin_nontemporal_store(v, &ob[(size_t)i * RW]);
    }
}

extern "C" void kernel_launch(void* const* d_in, const int* in_sizes, int n_in,
                              void* d_out, int out_size, void* d_ws, size_t ws_size,
                              hipStream_t stream) {
    const float* span1  = (const float*)d_in[0];
    const float* span2  = (const float*)d_in[1];
    const float* W_red  = (const float*)d_in[2];
    const float* b_red  = (const float*)d_in[3];
    const float* W_repr = (const float*)d_in[4];
    const float* b_repr = (const float*)d_in[5];
    float* out = (float*)d_out;

    // workspace carve (~6 MB)
    float* A1 = (float*)d_ws;                       // 512*1024 f32
    float* A2 = A1 + 512 * 1024;
    ushort_t* p = (ushort_t*)(A2 + 512 * 1024);
    ushort_t* r1h = p;  p += 512 * 512;
    ushort_t* r1l = p;  p += 512 * 512;
    ushort_t* r2h = p;  p += 512 * 512;
    ushort_t* r2l = p;  p += 512 * 512;

    const int M = B_ * N1_;   // 512

    // stage 1: r{1,2} = relu(span{1,2} @ W_red + b_red) -> hi/lo bf16
    gemm_fused<0><<<dim3(DRED_ / 64, M / 32, 2), 256, 0, stream>>>(
        span1, span2, nullptr, nullptr, nullptr, nullptr,
        W_red, 0, 0, b_red, b_red,
        r1h, r1l, r2h, r2l, nullptr, nullptr,
        M, DRED_, DIN_, DIN_, DRED_);

    // stage 2: A1 = r1 @ W_repr[0:512] + b_repr ; A2 = r2 @ W_repr[512:1024]
    gemm_fused<1><<<dim3(DREP_ / 64, M / 32, 2), 256, 0, stream>>>(
        nullptr, nullptr, r1h, r1l, r2h, r2l,
        W_repr, 0, DRED_, b_repr, nullptr,
        nullptr, nullptr, nullptr, nullptr, A1, A2,
        M, DREP_, DRED_, DRED_, DREP_);

    // stage 3: broadcast + relu (write-bound)
    bcast_relu<<<dim3(B_ * N1_ * (N2_ / 8)), 256, 0, stream>>>(
        (const f32x4*)A1, (const f32x4*)A2, (f32x4*)out);
}